// Round 1
// baseline (866.932 us; speedup 1.0000x reference)
//
#include <hip/hip_runtime.h>

// ---------------------------------------------------------------------------
// TemporalAttentionModule: B=64, C=2048, T=256, H=8, D=256 (== T)
//   q/k/v = W @ x + b   (per-batch GEMM, K=2048)
//   attn  = softmax(q k^T / 16);  out = attn @ v  -> (B, C, T) fp32
//
// ws layout (bytes):
//   [0,            67108864)  xT  bf16 [B][T][C]   (x transposed, k-major)
//   [67108864,     92274688)  Wbf bf16 [3][C][C]
//   [92274688,    293601280)  qkv bf16 [3][B][H][T][D]  (all stored d-major;
//                             for V this is V^T so PV is also a gemm_bt)
// ---------------------------------------------------------------------------

typedef __attribute__((ext_vector_type(8))) short    bf16x8;
typedef __attribute__((ext_vector_type(4))) float    f32x4;
typedef __attribute__((ext_vector_type(4))) unsigned short us4;
typedef __attribute__((ext_vector_type(8))) unsigned short us8;
typedef unsigned short u16;
typedef unsigned int   u32;

#define CC 2048
#define TT 256
#define BB 64
#define HH 8
#define DD 256

__device__ __forceinline__ u16 f2bf(float f) {
  u32 u = __builtin_bit_cast(u32, f);
  u32 r = (u + 0x7fffu + ((u >> 16) & 1u)) >> 16;
  return (u16)r;
}
__device__ __forceinline__ float bf2f(u16 b) {
  u32 u = ((u32)b) << 16;
  return __builtin_bit_cast(float, u);
}

__device__ __forceinline__ void async16(const void* g, void* l) {
  __builtin_amdgcn_global_load_lds(
      (const __attribute__((address_space(1))) u32*)g,
      (__attribute__((address_space(3))) u32*)l, 16, 0, 0);
}

// --------------------------- W fp32 -> bf16 --------------------------------
__global__ __launch_bounds__(256) void wconv_kernel(
    const float* __restrict__ w0, const float* __restrict__ w1,
    const float* __restrict__ w2, u16* __restrict__ dst) {
  int p = blockIdx.y;
  const float* s = (p == 0) ? w0 : (p == 1) ? w1 : w2;
  size_t i = ((size_t)blockIdx.x * 256 + threadIdx.x) * 4;
  float4 v = *(const float4*)(s + i);
  us4 o = {f2bf(v.x), f2bf(v.y), f2bf(v.z), f2bf(v.w)};
  *(us4*)(dst + (size_t)p * CC * CC + i) = o;
}

// ------------------ x (B,C,T) fp32 -> xT (B,T,C) bf16 ----------------------
__global__ __launch_bounds__(256) void xt_kernel(
    const float* __restrict__ x, u16* __restrict__ xT) {
  __shared__ float tile[64][68];
  int t0 = blockIdx.x * 64;
  int c0 = blockIdx.y * 64;
  int b  = blockIdx.z;
  int tid = threadIdx.x;
  int lr = tid >> 4;          // 0..15
  int lc = (tid & 15) * 4;    // t within tile
  const float* src = x + ((size_t)b * CC + c0) * TT + t0;
#pragma unroll
  for (int s = 0; s < 4; ++s) {
    int c = s * 16 + lr;
    float4 v = *(const float4*)(src + (size_t)c * TT + lc);
    *(float4*)&tile[c][lc] = v;
  }
  __syncthreads();
  int t  = tid >> 2;
  int cb = (tid & 3) * 16;
  u16 tmp[16];
#pragma unroll
  for (int e = 0; e < 16; ++e) tmp[e] = f2bf(tile[cb + e][t]);
  u16* dst = xT + ((size_t)b * TT + t0 + t) * CC + c0 + cb;
  *(us8*)dst       = *(const us8*)&tmp[0];
  *(us8*)(dst + 8) = *(const us8*)&tmp[8];
}

// --------------------- QKV projection GEMM (m97-style) ---------------------
// per block: 128(o) x 128(t) tile, K=2048 in 32-steps; output stored
// transposed into qkv[proj][b][h][t][d] with bias added.
__global__ __launch_bounds__(256) void proj_kernel(
    const u16* __restrict__ Wbf, const u16* __restrict__ xT,
    const float* __restrict__ bq, const float* __restrict__ bk,
    const float* __restrict__ bv, u16* __restrict__ qkv) {
  __shared__ __align__(16) u16 As[128 * 32];
  __shared__ __align__(16) u16 Bs[128 * 32];
  int tid = threadIdx.x;
  int m0 = blockIdx.x * 128;
  int t0 = blockIdx.y * 128;
  int z  = blockIdx.z;
  int proj = z >> 6;
  int b    = z & 63;
  const u16* A = Wbf + (size_t)proj * CC * CC;
  const u16* X = xT + (size_t)b * TT * CC;
  const float* bias = (proj == 0) ? bq : (proj == 1) ? bk : bv;
  u16* outp = qkv + (size_t)proj * BB * CC * TT;

  int lane = tid & 63, w = tid >> 6;
  int wm = w >> 1, wn = w & 1;
  int ar = lane & 15, kq = lane >> 4;

  int arow = tid >> 2;         // 0..63 (staging row)
  int acol = (tid & 3) * 8;    // k-chunk (elements)
  const u16* Abase = A + (size_t)(m0 + arow) * CC + acol;
  const u16* Xbase = X + (size_t)(t0 + arow) * CC + acol;

  f32x4 acc[4][4] = {};
  for (int k0 = 0; k0 < CC; k0 += 32) {
    async16(Abase + k0, As + tid * 8);
    async16(Abase + (size_t)64 * CC + k0, As + 2048 + tid * 8);
    async16(Xbase + k0, Bs + tid * 8);
    async16(Xbase + (size_t)64 * CC + k0, Bs + 2048 + tid * 8);
    __syncthreads();
    bf16x8 af[4], bfv[4];
#pragma unroll
    for (int mt = 0; mt < 4; ++mt)
      af[mt] = *(const bf16x8*)&As[(wm * 64 + mt * 16 + ar) * 32 + kq * 8];
#pragma unroll
    for (int nt = 0; nt < 4; ++nt)
      bfv[nt] = *(const bf16x8*)&Bs[(wn * 64 + nt * 16 + ar) * 32 + kq * 8];
#pragma unroll
    for (int mt = 0; mt < 4; ++mt)
#pragma unroll
      for (int nt = 0; nt < 4; ++nt)
        acc[mt][nt] = __builtin_amdgcn_mfma_f32_16x16x32_bf16(
            af[mt], bfv[nt], acc[mt][nt], 0, 0, 0);
    __syncthreads();
  }
  // epilogue: C row (m/o dim) = kq*4+reg, col (n/t dim) = ar; store C^T
#pragma unroll
  for (int mt = 0; mt < 4; ++mt) {
    int ob = m0 + wm * 64 + mt * 16 + kq * 4;   // o for reg 0..3
    float b0 = bias[ob], b1 = bias[ob + 1], b2 = bias[ob + 2], b3 = bias[ob + 3];
    int h = ob >> 8, d = ob & 255;
    u16* obase = outp + (((size_t)b * HH + h) * TT) * DD + d;
#pragma unroll
    for (int nt = 0; nt < 4; ++nt) {
      int t = t0 + wn * 64 + nt * 16 + ar;
      f32x4 v = acc[mt][nt];
      us4 pk = {f2bf(v[0] + b0), f2bf(v[1] + b1), f2bf(v[2] + b2),
                f2bf(v[3] + b3)};
      *(us4*)(obase + (size_t)t * DD) = pk;
    }
  }
}

// ----------------------------- fused attention -----------------------------
// block: one (b,h) pair, 64 q-rows. Phase1 S=QK^T in regs; exp (no max
// subtraction -- logits are O(1)); P bf16 -> padded LDS; rowsums via
// shfl_xor + LDS; Phase2 O = P V^T; epilogue multiplies by 1/rowsum.
__global__ __launch_bounds__(256) void attn_kernel(
    const u16* __restrict__ qkv, float* __restrict__ out) {
  __shared__ __align__(16) u16 As[64 * 32];
  __shared__ __align__(16) u16 Bs[256 * 32];
  __shared__ __align__(16) u16 Ps[64 * 264];   // +8 pad: 2-way banks only
  __shared__ float rowpart[64][4];
  __shared__ float inv[64];

  int tid = threadIdx.x;
  int i0 = blockIdx.x * 64;
  int bh = blockIdx.y;                          // b*8 + h
  const size_t hd = (size_t)TT * DD;            // 65536
  const u16* Q = qkv + (size_t)bh * hd;
  const u16* K = qkv + (size_t)(BB * HH + bh) * hd;
  const u16* V = qkv + (size_t)(2 * BB * HH + bh) * hd;

  int lane = tid & 63, w = tid >> 6;
  int ar = lane & 15, kq = lane >> 4;
  int arow = tid >> 2, acol = (tid & 3) * 8;

  const u16* Qbase = Q + (size_t)(i0 + arow) * DD + acol;
  const u16* Kbase = K + (size_t)arow * DD + acol;
  const u16* Vbase = V + (size_t)arow * DD + acol;

  f32x4 acc[4][4] = {};
  // ---- phase 1: S = Q K^T ----
  for (int k0 = 0; k0 < DD; k0 += 32) {
    async16(Qbase + k0, As + tid * 8);
#pragma unroll
    for (int s = 0; s < 4; ++s)
      async16(Kbase + (size_t)(s * 64) * DD + k0, Bs + s * 2048 + tid * 8);
    __syncthreads();
    bf16x8 af[4], bfv[4];
#pragma unroll
    for (int mt = 0; mt < 4; ++mt)
      af[mt] = *(const bf16x8*)&As[(mt * 16 + ar) * 32 + kq * 8];
#pragma unroll
    for (int nt = 0; nt < 4; ++nt)
      bfv[nt] = *(const bf16x8*)&Bs[(w * 64 + nt * 16 + ar) * 32 + kq * 8];
#pragma unroll
    for (int mt = 0; mt < 4; ++mt)
#pragma unroll
      for (int nt = 0; nt < 4; ++nt)
        acc[mt][nt] = __builtin_amdgcn_mfma_f32_16x16x32_bf16(
            af[mt], bfv[nt], acc[mt][nt], 0, 0, 0);
    __syncthreads();
  }
  // ---- exp + P to LDS + row partial sums ----
  const float scale = 0.0625f;
#pragma unroll
  for (int mt = 0; mt < 4; ++mt) {
    float ps[4] = {0.f, 0.f, 0.f, 0.f};
#pragma unroll
    for (int nt = 0; nt < 4; ++nt) {
      f32x4 v = acc[mt][nt];
#pragma unroll
      for (int r = 0; r < 4; ++r) {
        float p = __expf(v[r] * scale);
        u16 pb = f2bf(p);
        Ps[(mt * 16 + kq * 4 + r) * 264 + (w * 64 + nt * 16 + ar)] = pb;
        ps[r] += bf2f(pb);   // sum the rounded value for consistency
      }
    }
#pragma unroll
    for (int r = 0; r < 4; ++r) {
      float s = ps[r];
      s += __shfl_xor(s, 1, 64);
      s += __shfl_xor(s, 2, 64);
      s += __shfl_xor(s, 4, 64);
      s += __shfl_xor(s, 8, 64);
      if (ar == 0) rowpart[mt * 16 + kq * 4 + r][w] = s;
    }
  }
  __syncthreads();
  if (tid < 64) {
    float s = rowpart[tid][0] + rowpart[tid][1] + rowpart[tid][2] +
              rowpart[tid][3];
    inv[tid] = 1.0f / s;
  }
  // ---- phase 2: O = P V^T ----
#pragma unroll
  for (int mt = 0; mt < 4; ++mt)
#pragma unroll
    for (int nt = 0; nt < 4; ++nt) acc[mt][nt] = (f32x4){0.f, 0.f, 0.f, 0.f};
  for (int k0 = 0; k0 < TT; k0 += 32) {
#pragma unroll
    for (int s = 0; s < 4; ++s)
      async16(Vbase + (size_t)(s * 64) * DD + k0, Bs + s * 2048 + tid * 8);
    __syncthreads();
    bf16x8 af[4], bfv[4];
#pragma unroll
    for (int mt = 0; mt < 4; ++mt)
      af[mt] = *(const bf16x8*)&Ps[(mt * 16 + ar) * 264 + k0 + kq * 8];
#pragma unroll
    for (int nt = 0; nt < 4; ++nt)
      bfv[nt] = *(const bf16x8*)&Bs[(w * 64 + nt * 16 + ar) * 32 + kq * 8];
#pragma unroll
    for (int mt = 0; mt < 4; ++mt)
#pragma unroll
      for (int nt = 0; nt < 4; ++nt)
        acc[mt][nt] = __builtin_amdgcn_mfma_f32_16x16x32_bf16(
            af[mt], bfv[nt], acc[mt][nt], 0, 0, 0);
    __syncthreads();
  }
  // ---- epilogue: normalize rows, store fp32 ----
  int b = bh >> 3, h = bh & 7;
  float* obase = out + ((size_t)b * CC + h * TT + i0) * TT;
#pragma unroll
  for (int mt = 0; mt < 4; ++mt)
#pragma unroll
    for (int r = 0; r < 4; ++r) {
      int m = mt * 16 + kq * 4 + r;
      float iv = inv[m];
#pragma unroll
      for (int nt = 0; nt < 4; ++nt) {
        int n = w * 64 + nt * 16 + ar;
        obase[(size_t)m * TT + n] = acc[mt][nt][r] * iv;
      }
    }
}

// ---------------------------------------------------------------------------
extern "C" void kernel_launch(void* const* d_in, const int* in_sizes, int n_in,
                              void* d_out, int out_size, void* d_ws,
                              size_t ws_size, hipStream_t stream) {
  const float* x  = (const float*)d_in[0];
  const float* Wq = (const float*)d_in[1];
  const float* bq = (const float*)d_in[2];
  const float* Wk = (const float*)d_in[3];
  const float* bk = (const float*)d_in[4];
  const float* Wv = (const float*)d_in[5];
  const float* bv = (const float*)d_in[6];
  float* out = (float*)d_out;

  char* ws = (char*)d_ws;
  u16* xT  = (u16*)ws;                               // 64 MiB
  u16* Wbf = (u16*)(ws + 67108864);                  // 24 MiB
  u16* qkv = (u16*)(ws + 67108864 + 25165824);       // 192 MiB

  wconv_kernel<<<dim3(4096, 3, 1), 256, 0, stream>>>(Wq, Wk, Wv, Wbf);
  xt_kernel<<<dim3(4, 32, 64), 256, 0, stream>>>(x, xT);
  proj_kernel<<<dim3(16, 2, 192), 256, 0, stream>>>(Wbf, xT, bq, bk, bv, qkv);
  attn_kernel<<<dim3(4, 512, 1), 256, 0, stream>>>(qkv, out);
}